// Round 17
// baseline (85.835 us; speedup 1.0000x reference)
//
#include <hip/hip_runtime.h>

#define B 64
#define T 4096
#define AD 1024   // ATTN_RNN_DIM
#define HD 256    // HYPERNET_DIM
#define CH 32
#define KS 31
#define OD 128
#define PADW 15
#define CWN (CH*KS)   // 992
#define TILE_T 128
#define NTILE (T / TILE_T)   // 32

// LDS-only barrier: orders ds_write->ds_read without draining global stores
#define LDS_BARRIER() asm volatile("s_waitcnt lgkmcnt(0)\n\ts_barrier" ::: "memory")

// ---------------- Merged front: ONE dispatch. Block (b,q) recomputes h[b,:]
// itself (4x redundancy, W1 is L2-resident), then its cw slice + G stage.
// No cross-block dependency -> no sync hazards.
__global__ __launch_bounds__(256) void k_front(
        const float* __restrict__ qry, const float* __restrict__ W1,
        const float* __restrict__ b1,  const float* __restrict__ W2,
        const float* __restrict__ b2,  const float* __restrict__ Wfc,
        float* __restrict__ Gt) {
    int b  = blockIdx.x >> 2;
    int qq = blockIdx.x & 3;
    int tid = threadIdx.x;
    int lane = tid & 63, w = tid >> 6;
    __shared__ float qs[AD];           // 4 KB
    __shared__ float hs[HD];           // 1 KB
    __shared__ float cwl[CH * 8];      // 1 KB
    __shared__ float wfs_t[CH * OD];   // 16 KB, [c][o]

    #pragma unroll
    for (int p = 0; p < 4; ++p)
        qs[p * 256 + tid] = qry[(size_t)b * AD + p * 256 + tid];
    #pragma unroll
    for (int p = 0; p < 16; ++p) {
        int idx = p * 256 + tid;
        int o = idx >> 5, c = idx & 31;
        wfs_t[c * OD + o] = Wfc[idx];
    }
    __syncthreads();

    // h[b,:]: wave w owns 64 j's; coalesced W1 rows + shfl reduce
    const float4* qs4 = (const float4*)qs;
    for (int i = 0; i < 64; ++i) {
        int j = w * 64 + i;
        const float4* wr = (const float4*)(W1 + (size_t)j * AD);
        float s = 0.f;
        #pragma unroll
        for (int m = 0; m < 4; ++m) {
            float4 wv = wr[m * 64 + lane];
            float4 qv = qs4[m * 64 + lane];
            s += wv.x*qv.x + wv.y*qv.y + wv.z*qv.z + wv.w*qv.w;
        }
        #pragma unroll
        for (int off = 32; off > 0; off >>= 1)
            s += __shfl_down(s, off, 64);
        if (lane == 0) hs[j] = tanhf(s + b1[j]);
    }
    __syncthreads();

    // cw slice: thread (c, kk) -> row c*KS + (qq*8+kk)
    {
        int c = tid >> 3, kk = tid & 7;
        int k = qq * 8 + kk;
        if (k < KS) {
            int r = c * KS + k;
            const float4* wr  = (const float4*)(W2 + (size_t)r * HD);
            const float4* hs4 = (const float4*)hs;
            float s = 0.f;
            #pragma unroll
            for (int m = 0; m < HD / 4; ++m) {
                float4 wv = wr[m], hv = hs4[m];
                s += wv.x*hv.x + wv.y*hv.y + wv.z*hv.z + wv.w*hv.w;
            }
            cwl[c * 8 + kk] = s + b2[r];
        }
    }
    __syncthreads();

    // G: Gt[b, kg*OD+o] = sum_c wfs_t[c][o] * cwl[c][kl]
    #pragma unroll
    for (int p = 0; p < 4; ++p) {
        int idx = p * 256 + tid;
        int kl = idx >> 7, o = idx & 127;
        int kg = qq * 8 + kl;
        if (kg < KS) {
            float s = 0.f;
            #pragma unroll
            for (int c = 0; c < CH; ++c)
                s += wfs_t[c * OD + o] * cwl[c * 8 + kl];   // bcast + stride-1
            Gt[(size_t)b * (KS * OD) + kg * OD + o] = s;
        }
    }
}

// ---------------- Conv (byte-identical to R15): out = conv(pa, G) + bfc
__device__ __forceinline__ void compute_chunk(const float* pa, int s0, float base,
                                              const float (&g)[KS], float (&acc)[8]) {
    float pw[40];
    const float4* lp = (const float4*)(pa + s0);   // s0 % 8 == 0 -> aligned
    #pragma unroll
    for (int q4 = 0; q4 < 10; ++q4) {
        float4 v = lp[q4];
        pw[q4*4+0] = v.x; pw[q4*4+1] = v.y; pw[q4*4+2] = v.z; pw[q4*4+3] = v.w;
    }
    #pragma unroll
    for (int tt = 0; tt < 8; ++tt) {
        float a = base;
        #pragma unroll
        for (int k = 0; k < KS; ++k)
            a += g[k] * pw[tt + k];
        acc[tt] = a;
    }
}

__global__ __launch_bounds__(256, 4) void k_conv(const float* __restrict__ pa_g,
        const float* __restrict__ Gt, const float* __restrict__ bfc,
        float* __restrict__ out) {
    int bid  = blockIdx.x;
    int sid  = (bid & 7) * 256 + (bid >> 3);
    int b    = sid >> 5;          // 32 tiles per b
    int tile = sid & 31;
    int t0   = tile * TILE_T;
    int tid  = threadIdx.x;
    __shared__ float tileo[64][128];      // 32 KB
    __shared__ float pa[TILE_T + 32];     // 158 used

    if (tid < TILE_T + 30) {
        int gg = t0 + tid - PADW;
        pa[tid] = (gg >= 0 && gg < T) ? pa_g[(size_t)b * T + gg] : 0.f;
    }
    int o = tid & 127, half = tid >> 7;
    float g[KS];
    #pragma unroll
    for (int k = 0; k < KS; ++k)
        g[k] = Gt[(size_t)b * (KS * OD) + k * OD + o];   // coalesced, L2-hot
    float base = bfc[o];
    __syncthreads();

    #pragma unroll
    for (int pass = 0; pass < 2; ++pass) {
        const float* pap = pa + pass * 64;               // keeps 16B alignment
        size_t obase = ((size_t)b * T + t0 + pass * 64) * OD;
        #pragma unroll
        for (int c = 0; c < 4; ++c) {
            int s0 = half * 32 + c * 8;
            float acc[8];
            compute_chunk(pap, s0, base, g, acc);
            #pragma unroll
            for (int tt = 0; tt < 8; ++tt)
                tileo[s0 + tt][o] = acc[tt];             // 2-way alias: free
            LDS_BARRIER();
            #pragma unroll
            for (int j = 0; j < 2; ++j) {
                int f  = j * 256 + tid;
                int rl = f >> 5, c4 = f & 31;
                int row = (j == 0) ? (c * 8 + rl) : (32 + c * 8 + (rl - 8));
                float4 v = *(const float4*)&tileo[row][c4 * 4];
                *(float4*)(out + obase + (size_t)row * OD + c4 * 4) = v;
            }
        }
    }
}

extern "C" void kernel_launch(void* const* d_in, const int* in_sizes, int n_in,
                              void* d_out, int out_size, void* d_ws, size_t ws_size,
                              hipStream_t stream) {
    const float* query = (const float*)d_in[0];
    const float* prev  = (const float*)d_in[1];
    const float* W1    = (const float*)d_in[2];
    const float* b1    = (const float*)d_in[3];
    const float* W2    = (const float*)d_in[4];
    const float* b2    = (const float*)d_in[5];
    const float* Wfc   = (const float*)d_in[6];
    const float* bfc   = (const float*)d_in[7];
    float* out = (float*)d_out;

    float* Gt = (float*)d_ws;          // 64*3968 floats

    k_front<<<dim3(B * 4), dim3(256), 0, stream>>>(query, W1, b1, W2, b2, Wfc, Gt);
    k_conv <<<dim3(B * NTILE), dim3(256), 0, stream>>>(prev, Gt, bfc, out);
}

// Round 18
// 51.381 us; speedup vs baseline: 1.6705x; 1.6705x over previous
//
#include <hip/hip_runtime.h>

#define B 64
#define T 4096
#define AD 1024   // ATTN_RNN_DIM
#define HD 256    // HYPERNET_DIM
#define CH 32
#define KS 31
#define OD 128
#define PADW 15
#define CWN (CH*KS)   // 992
#define TILE_T 128
#define NTILE (T / TILE_T)   // 32

// LDS-only barrier: orders ds_write->ds_read without draining global stores
#define LDS_BARRIER() asm volatile("s_waitcnt lgkmcnt(0)\n\ts_barrier" ::: "memory")

// ---------------- Kernel A: h[b,j] = tanh(dot(query[b,:], W1[j,:]) + b1[j])
// 1024 blocks: block = (b, 16-j group); q[b] staged once in LDS; 4 j per wave
__global__ __launch_bounds__(256) void k_hyper1(const float* __restrict__ q,
        const float* __restrict__ W1, const float* __restrict__ b1,
        float* __restrict__ h) {
    int bid  = blockIdx.x;            // 0..1023
    int tid  = threadIdx.x;
    int lane = tid & 63, w = tid >> 6;
    int b  = bid >> 4;                // 16 blocks per b
    int jb = (bid & 15) * 16;         // this block's 16 j's
    __shared__ float qs[AD];          // 4 KB
    #pragma unroll
    for (int p = 0; p < 4; ++p)
        qs[p * 256 + tid] = q[(size_t)b * AD + p * 256 + tid];
    __syncthreads();
    const float4* qs4 = (const float4*)qs;
    #pragma unroll
    for (int r = 0; r < 4; ++r) {
        int j = jb + w * 4 + r;
        const float4* wr = (const float4*)(W1 + (size_t)j * AD);
        float s = 0.f;
        #pragma unroll
        for (int m = 0; m < 4; ++m) {
            float4 wv = wr[m * 64 + lane];
            float4 qv = qs4[m * 64 + lane];
            s += wv.x*qv.x + wv.y*qv.y + wv.z*qv.z + wv.w*qv.w;
        }
        #pragma unroll
        for (int off = 32; off > 0; off >>= 1)
            s += __shfl_down(s, off, 64);
        if (lane == 0) h[(size_t)b * HD + j] = tanhf(s + b1[j]);
    }
}

// ---------------- Kernel B (fused cw+G): block (b,q) owns k in [8q, min(8q+8,31))
__global__ __launch_bounds__(256) void k_cwG(const float* __restrict__ h,
        const float* __restrict__ W2, const float* __restrict__ b2,
        const float* __restrict__ Wfc, float* __restrict__ Gt) {
    int b = blockIdx.x >> 2;
    int q = blockIdx.x & 3;
    int tid = threadIdx.x;
    __shared__ float hs[HD];           // 1 KB
    __shared__ float cwl[CH * 8];      // [c][kk], 1 KB
    __shared__ float wfs_t[CH * OD];   // [c][o], 16 KB
    hs[tid] = h[(size_t)b * HD + tid];
    #pragma unroll
    for (int p = 0; p < 16; ++p) {
        int idx = p * 256 + tid;
        int o = idx >> 5, c = idx & 31;
        wfs_t[c * OD + o] = Wfc[idx];
    }
    __syncthreads();
    {
        int c = tid >> 3, kk = tid & 7;
        int k = q * 8 + kk;
        if (k < KS) {
            int r = c * KS + k;
            const float4* wr  = (const float4*)(W2 + (size_t)r * HD);
            const float4* hs4 = (const float4*)hs;
            float s = 0.f;
            #pragma unroll
            for (int m = 0; m < HD / 4; ++m) {
                float4 w = wr[m], hv = hs4[m];
                s += w.x * hv.x + w.y * hv.y + w.z * hv.z + w.w * hv.w;
            }
            cwl[c * 8 + kk] = s + b2[r];
        }
    }
    __syncthreads();
    #pragma unroll
    for (int p = 0; p < 4; ++p) {
        int idx = p * 256 + tid;
        int kl = idx >> 7, o = idx & 127;
        int kg = q * 8 + kl;
        if (kg < KS) {
            float s = 0.f;
            #pragma unroll
            for (int c = 0; c < CH; ++c)
                s += wfs_t[c * OD + o] * cwl[c * 8 + kl];   // bcast + stride-1
            Gt[(size_t)b * (KS * OD) + kg * OD + o] = s;
        }
    }
}

// ---------------- Kernel C: out[b,t,o] = sum_k Gt[b,k,o]*pa[b,t+k-15] + bfc[o]
// 16KB staging tile (32 rows), 5 blocks/CU (20 waves) for more TLP
__device__ __forceinline__ void compute_chunk(const float* pa, int s0, float base,
                                              const float (&g)[KS], float (&acc)[8]) {
    float pw[40];
    const float4* lp = (const float4*)(pa + s0);   // s0 % 8 == 0 -> aligned
    #pragma unroll
    for (int q4 = 0; q4 < 10; ++q4) {
        float4 v = lp[q4];
        pw[q4*4+0] = v.x; pw[q4*4+1] = v.y; pw[q4*4+2] = v.z; pw[q4*4+3] = v.w;
    }
    #pragma unroll
    for (int tt = 0; tt < 8; ++tt) {
        float a = base;
        #pragma unroll
        for (int k = 0; k < KS; ++k)
            a += g[k] * pw[tt + k];
        acc[tt] = a;
    }
}

__global__ __launch_bounds__(256, 5) void k_conv(const float* __restrict__ pa_g,
        const float* __restrict__ Gt, const float* __restrict__ bfc,
        float* __restrict__ out) {
    // XCD swizzle: grid 2048 = 8 XCDs x 256; each XCD gets 8 whole batches
    int bid  = blockIdx.x;
    int sid  = (bid & 7) * 256 + (bid >> 3);
    int b    = sid >> 5;          // 32 tiles per b
    int tile = sid & 31;
    int t0   = tile * TILE_T;
    int tid  = threadIdx.x;
    __shared__ float tileo[32][128];      // 16 KB (was 32 KB)
    __shared__ float pa[TILE_T + 32];     // 158 used

    if (tid < TILE_T + 30) {
        int gg = t0 + tid - PADW;
        pa[tid] = (gg >= 0 && gg < T) ? pa_g[(size_t)b * T + gg] : 0.f;
    }
    int o = tid & 127, half = tid >> 7;
    float g[KS];
    #pragma unroll
    for (int k = 0; k < KS; ++k)
        g[k] = Gt[(size_t)b * (KS * OD) + k * OD + o];   // coalesced, L2-hot
    float base = bfc[o];
    __syncthreads();

    // 4 windows of 32 t-rows; per window: each half computes 2 chunks of 8,
    // barrier, cooperative wide store of the 32 rows, barrier (read-drain)
    #pragma unroll
    for (int w = 0; w < 4; ++w) {
        const float* paw = pa + w * 32;                  // 16B-aligned
        size_t obase = ((size_t)b * T + t0 + w * 32) * OD;
        #pragma unroll
        for (int cc = 0; cc < 2; ++cc) {
            int r0 = half * 16 + cc * 8;                 // row in window [0,32)
            float acc[8];
            compute_chunk(paw, r0, base, g, acc);
            #pragma unroll
            for (int tt = 0; tt < 8; ++tt)
                tileo[r0 + tt][o] = acc[tt];             // 2-way alias: free
        }
        LDS_BARRIER();   // LDS-only: global stores keep flying
        #pragma unroll
        for (int it = 0; it < 4; ++it) {
            int f  = it * 256 + tid;
            int rl = f >> 5, c4 = f & 31;
            float4 v = *(const float4*)&tileo[rl][c4 * 4];
            *(float4*)(out + obase + (size_t)rl * OD + c4 * 4) = v;
        }
        LDS_BARRIER();   // ds_reads drained before next window's ds_writes
    }
}

extern "C" void kernel_launch(void* const* d_in, const int* in_sizes, int n_in,
                              void* d_out, int out_size, void* d_ws, size_t ws_size,
                              hipStream_t stream) {
    const float* query = (const float*)d_in[0];
    const float* prev  = (const float*)d_in[1];
    const float* W1    = (const float*)d_in[2];
    const float* b1    = (const float*)d_in[3];
    const float* W2    = (const float*)d_in[4];
    const float* b2    = (const float*)d_in[5];
    const float* Wfc   = (const float*)d_in[6];
    const float* bfc   = (const float*)d_in[7];
    float* out = (float*)d_out;

    float* h  = (float*)d_ws;          // 16384 floats
    float* Gt = h + B * HD;            // 253952 floats

    k_hyper1<<<dim3(B * 16), dim3(256), 0, stream>>>(query, W1, b1, h);
    k_cwG   <<<dim3(B * 4), dim3(256), 0, stream>>>(h, W2, b2, Wfc, Gt);
    k_conv  <<<dim3(B * NTILE), dim3(256), 0, stream>>>(prev, Gt, bfc, out);
}